// Round 5
// baseline (213.614 us; speedup 1.0000x reference)
//
#include <hip/hip_runtime.h>
#include <hip/hip_bf16.h>
#include <stdint.h>
#include <math.h>

#define NTOK 4096
#define DIM 768
#define FF 3072
#define NE 4

typedef __attribute__((ext_vector_type(8))) short bf16x8;
typedef __attribute__((ext_vector_type(4))) float f32x4;
typedef unsigned short u16;

static __device__ __forceinline__ u16 f2bf(float f) {
    union { float f; unsigned u; } c; c.f = f;
    unsigned r = (c.u + 0x7FFFu + ((c.u >> 16) & 1u)) >> 16;
    return (u16)r;
}

// Abramowitz-Stegun 7.1.26, |abs err| <= 1.5e-7 (beyond bf16 grain)
static __device__ __forceinline__ float fast_erff(float x) {
    float ax = fabsf(x);
    float t = 1.0f / (1.0f + 0.3275911f * ax);
    float p = ((((1.061405429f * t - 1.453152027f) * t) + 1.421413741f) * t
               - 0.284496736f) * t + 0.254829592f;
    float y = 1.0f - p * t * __expf(-ax * ax);
    return copysignf(y, x);
}

#define GLD_LDS16(g, l) __builtin_amdgcn_global_load_lds( \
    (const __attribute__((address_space(1))) void*)(g),   \
    (__attribute__((address_space(3))) void*)(l), 16, 0, 0)

// ------- gating (fused with x->bf16 conversion): logits, softmax, argmax, lists -------
__global__ __launch_bounds__(256) void gate_kernel(
    const float* __restrict__ x, const float* __restrict__ gw,
    float* __restrict__ probs, int* __restrict__ counts, int* __restrict__ tlist,
    int* __restrict__ eid, u16* __restrict__ xbf)
{
    const int wid = threadIdx.x >> 6, lane = threadIdx.x & 63;
    const int n = blockIdx.x * 4 + wid;
    const float4* xr4 = (const float4*)(x + (size_t)n * DIM);
    float a0 = 0.f, a1 = 0.f, a2 = 0.f, a3 = 0.f;
    float4 xv[3];
    #pragma unroll
    for (int c = 0; c < 3; c++) {
        float4 v = xr4[c * 64 + lane];
        xv[c] = v;
        const float4 g0 = ((const float4*)(gw + 0 * DIM))[c * 64 + lane];
        const float4 g1 = ((const float4*)(gw + 1 * DIM))[c * 64 + lane];
        const float4 g2 = ((const float4*)(gw + 2 * DIM))[c * 64 + lane];
        const float4 g3 = ((const float4*)(gw + 3 * DIM))[c * 64 + lane];
        a0 += v.x * g0.x + v.y * g0.y + v.z * g0.z + v.w * g0.w;
        a1 += v.x * g1.x + v.y * g1.y + v.z * g1.z + v.w * g1.w;
        a2 += v.x * g2.x + v.y * g2.y + v.z * g2.z + v.w * g2.w;
        a3 += v.x * g3.x + v.y * g3.y + v.z * g3.z + v.w * g3.w;
    }
    #pragma unroll
    for (int c = 0; c < 3; c++) {
        ushort4 o;
        o.x = f2bf(xv[c].x); o.y = f2bf(xv[c].y);
        o.z = f2bf(xv[c].z); o.w = f2bf(xv[c].w);
        *(ushort4*)(xbf + (size_t)n * DIM + (c * 64 + lane) * 4) = o;
    }
    #pragma unroll
    for (int off = 32; off > 0; off >>= 1) {
        a0 += __shfl_xor(a0, off);
        a1 += __shfl_xor(a1, off);
        a2 += __shfl_xor(a2, off);
        a3 += __shfl_xor(a3, off);
    }
    if (lane == 0) {
        float l[4] = {a0, a1, a2, a3};
        float m = fmaxf(fmaxf(l[0], l[1]), fmaxf(l[2], l[3]));
        float p[4], s = 0.f;
        #pragma unroll
        for (int e = 0; e < 4; e++) { p[e] = expf(l[e] - m); s += p[e]; }
        float inv = 1.f / s;
        int amax = 0; float best = l[0];
        #pragma unroll
        for (int e = 1; e < 4; e++) if (l[e] > best) { best = l[e]; amax = e; }
        #pragma unroll
        for (int e = 0; e < 4; e++) probs[n * 4 + e] = p[e] * inv;
        eid[n] = amax;
        int pos = atomicAdd(&counts[amax], 1);
        tlist[amax * NTOK + pos] = n;
    }
}

// ---------------- balance loss + gate_load tail outputs ----------------
__global__ __launch_bounds__(256) void finalize_kernel(
    const float4* __restrict__ probs4, const int* __restrict__ counts,
    float* __restrict__ tail)
{
    __shared__ float sdata[256 * 4];
    float p0 = 0.f, p1 = 0.f, p2 = 0.f, p3 = 0.f;
    for (int n = threadIdx.x; n < NTOK; n += 256) {
        float4 v = probs4[n];
        p0 += v.x; p1 += v.y; p2 += v.z; p3 += v.w;
    }
    sdata[threadIdx.x * 4 + 0] = p0;
    sdata[threadIdx.x * 4 + 1] = p1;
    sdata[threadIdx.x * 4 + 2] = p2;
    sdata[threadIdx.x * 4 + 3] = p3;
    __syncthreads();
    for (int s = 128; s > 0; s >>= 1) {
        if ((int)threadIdx.x < s) {
            #pragma unroll
            for (int e = 0; e < 4; e++)
                sdata[threadIdx.x * 4 + e] += sdata[(threadIdx.x + s) * 4 + e];
        }
        __syncthreads();
    }
    if (threadIdx.x == 0) {
        float bl = 0.f;
        #pragma unroll
        for (int e = 0; e < 4; e++)
            bl += (sdata[e] / (float)NTOK) * ((float)counts[e] / (float)NTOK);
        bl *= (float)NE;
        tail[0] = bl;
        #pragma unroll
        for (int e = 0; e < 4; e++) tail[1 + e] = (float)counts[e];
    }
}

// ---- fp32 [E][R][C] -> bf16 [E][C][R] transpose, vectorized both sides ----
__global__ __launch_bounds__(256) void transpose_convert_kernel(
    const float* __restrict__ in, u16* __restrict__ out, int R, int C)
{
    __shared__ float tile[64 * 65];
    const int e = blockIdx.z;
    const float* src = in + (size_t)e * R * C;
    u16* dst = out + (size_t)e * R * C;
    const int r0 = blockIdx.y * 64, c0 = blockIdx.x * 64;
    #pragma unroll
    for (int p = 0; p < 4; ++p) {
        int f = p * 256 + threadIdx.x;
        int row = f >> 4, c4 = (f & 15) * 4;
        float4 v = *(const float4*)(src + (size_t)(r0 + row) * C + c0 + c4);
        tile[row * 65 + c4 + 0] = v.x;
        tile[row * 65 + c4 + 1] = v.y;
        tile[row * 65 + c4 + 2] = v.z;
        tile[row * 65 + c4 + 3] = v.w;
    }
    __syncthreads();
    #pragma unroll
    for (int p = 0; p < 2; ++p) {
        int u = p * 256 + threadIdx.x;
        int orow = u >> 3, g = (u & 7) * 8;
        bf16x8 v;
        #pragma unroll
        for (int j = 0; j < 8; ++j)
            v[j] = (short)f2bf(tile[(g + j) * 65 + orow]);
        *(bf16x8*)(dst + (size_t)(c0 + orow) * R + r0 + g) = v;
    }
}

// ---------------- out := bias row per token's expert (split-K atomic base) ----------------
__global__ __launch_bounds__(256) void init_out_kernel(
    const float* __restrict__ b2, const int* __restrict__ eid,
    float4* __restrict__ out4)
{
    int idx = blockIdx.x * 256 + threadIdx.x;
    int n = idx / (DIM / 4);
    int c = idx % (DIM / 4);
    int e = eid[n];
    out4[idx] = ((const float4*)(b2 + (size_t)e * DIM))[c];
}

// ---- grouped MFMA GEMM, 128x128 tile, 4 waves, depth-2 counted-vmcnt, 3 LDS bufs ----
// Work mapping: bx = rt*96 + q, q in [0,96), xcd = q&7 (96%8==0 keeps bx&7 == xcd).
// rt is SLOWEST-varying so working blocks (rt < ceil(cnt/128)) are the first launched
// -> spread evenly across all CUs (previous rounds clustered them on 1/4 of CUs).
//   MODE 0 (GEMM1): e = xcd>>1, ct = (xcd&1)*12 + (q>>3), ks = 0.         KSPLIT=1
//   MODE 1 (GEMM2): e = xcd>>1, ks = (xcd&1)*2 + (q>>3)/6, ct = (q>>3)%6. KSPLIT=4
template <int KD, int NCOL, int KSPLIT, int GELU_EP, int MODE>
__global__ __launch_bounds__(256, 3) void moe_gemm(
    const u16* __restrict__ A, const u16* __restrict__ Bt,
    const float* __restrict__ bias, const int* __restrict__ counts,
    const int* __restrict__ tlist, u16* __restrict__ Hout,
    float* __restrict__ Fout)
{
    constexpr int KSUB = KD / KSPLIT;
    constexpr int NS = KSUB / 32;
    constexpr int CTN = NCOL / 128;

    const int xcd = blockIdx.x & 7;
    const int q = (blockIdx.x >> 3) % 12;
    const int rt = blockIdx.x / 96;
    const int e = xcd >> 1;
    int ct, ks;
    if (MODE == 0) {
        ks = 0;
        ct = (xcd & 1) * (CTN / 2) + q;
    } else {
        ks = (xcd & 1) * 2 + q / 6;
        ct = q % 6;
    }

    const int cnt = counts[e];
    if (rt * 128 >= cnt) return;
    const int nvalid = min(128, cnt - rt * 128);
    const int* list = tlist + e * NTOK + rt * 128;
    const int ksoff = ks * KSUB;

    __shared__ __align__(16) u16 As[3][4096];
    __shared__ __align__(16) u16 Bs[3][4096];

    const int tid = threadIdx.x;
    const int lane = tid & 63;
    const int w = tid >> 6;

    // staging: slots cover LDS bytes q*16; inverse-swizzled source addresses
    const int cp = tid & 3;
    const int rp0 = tid >> 2, rp1 = 64 + rp0;
    const int r0s = rp0 ^ ((rp0 >> 2) & 1);
    const int r1s = rp1 ^ ((rp1 >> 2) & 1);
    const int cc0 = cp ^ (r0s & 3);
    const int cc1 = cp ^ (r1s & 3);
    const u16* pA0 = A + (size_t)list[min(r0s, nvalid - 1)] * KD + ksoff + cc0 * 8;
    const u16* pA1 = A + (size_t)list[min(r1s, nvalid - 1)] * KD + ksoff + cc1 * 8;
    const u16* Bbase = Bt + ((size_t)e * NCOL + (size_t)ct * 128) * KD + ksoff;
    const u16* pB0 = Bbase + (size_t)r0s * KD + cc0 * 8;
    const u16* pB1 = Bbase + (size_t)r1s * KD + cc1 * 8;
    const int dst0 = w * 512;
    const int dst1 = 2048 + w * 512;

    const int wm = w >> 1, wn = w & 1;
    const int fr = lane & 15, fg = lane >> 4;
    const int laneoff = (fr * 64 + fg * 16) ^ ((fr & 7) << 4);

    f32x4 acc[4][4];
    #pragma unroll
    for (int i = 0; i < 4; i++)
        #pragma unroll
        for (int j = 0; j < 4; j++) acc[i][j] = (f32x4){0.f, 0.f, 0.f, 0.f};

    auto stage = [&](int T) {
        const int b = T % 3, ko = T * 32;
        GLD_LDS16(pA0 + ko, &As[b][dst0]);
        GLD_LDS16(pA1 + ko, &As[b][dst1]);
        GLD_LDS16(pB0 + ko, &Bs[b][dst0]);
        GLD_LDS16(pB1 + ko, &Bs[b][dst1]);
    };
    auto compute = [&](int T) {
        const char* Ab = (const char*)&As[T % 3][0];
        const char* Bb = (const char*)&Bs[T % 3][0];
        bf16x8 af[4], bg[4];
        #pragma unroll
        for (int m4 = 0; m4 < 4; m4++)
            af[m4] = *(const bf16x8*)(Ab + wm * 4096 + m4 * 1024 + laneoff);
        #pragma unroll
        for (int n4 = 0; n4 < 4; n4++)
            bg[n4] = *(const bf16x8*)(Bb + wn * 4096 + n4 * 1024 + laneoff);
        #pragma unroll
        for (int m4 = 0; m4 < 4; m4++)
            #pragma unroll
            for (int n4 = 0; n4 < 4; n4++)
                acc[m4][n4] = __builtin_amdgcn_mfma_f32_16x16x32_bf16(
                    af[m4], bg[n4], acc[m4][n4], 0, 0, 0);
    };

    // prologue: tiles 0,1 in flight (8 vmem ops/wave)
    stage(0); stage(1);

    for (int t = 0; t < NS; ++t) {
        if (t < NS - 1)
            asm volatile("s_waitcnt vmcnt(4)" ::: "memory");
        else
            asm volatile("s_waitcnt vmcnt(0)" ::: "memory");
        __builtin_amdgcn_sched_barrier(0);
        __builtin_amdgcn_s_barrier();
        __builtin_amdgcn_sched_barrier(0);
        if (t + 2 < NS) stage(t + 2);
        compute(t);
    }

    // ---- epilogue: C/D layout col = lane&15 (fr), row = fg*4 + reg ----
    #pragma unroll
    for (int m4 = 0; m4 < 4; m4++) {
        const int rowbase = wm * 64 + m4 * 16 + fg * 4;
        #pragma unroll
        for (int r2 = 0; r2 < 4; r2++) {
            const int row = rowbase + r2;
            if (row < nvalid) {
                const int tok = list[row];
                #pragma unroll
                for (int n4 = 0; n4 < 4; n4++) {
                    const int col = ct * 128 + wn * 64 + n4 * 16 + fr;
                    float v = acc[m4][n4][r2];
                    if (GELU_EP) {
                        v += bias[e * NCOL + col];
                        v = 0.5f * v * (1.f + fast_erff(v * 0.70710678118654752f));
                        Hout[(size_t)tok * NCOL + col] = f2bf(v);
                    } else {
                        atomicAdd(&Fout[(size_t)tok * NCOL + col], v);
                    }
                }
            }
        }
    }
}

extern "C" void kernel_launch(void* const* d_in, const int* in_sizes, int n_in,
                              void* d_out, int out_size, void* d_ws, size_t ws_size,
                              hipStream_t stream) {
    const float* x  = (const float*)d_in[0];
    const float* gw = (const float*)d_in[3];
    const float* W1 = (const float*)d_in[4];
    const float* b1 = (const float*)d_in[5];
    const float* W2 = (const float*)d_in[6];
    const float* b2 = (const float*)d_in[7];
    float* out = (float*)d_out;

    char* ws = (char*)d_ws;
    size_t o = 0;
    auto alloc = [&](size_t bytes) -> void* {
        void* p = ws + o;
        o = (o + bytes + 255) & ~(size_t)255;
        return p;
    };
    u16*   xbf    = (u16*)alloc((size_t)NTOK * DIM * 2);
    u16*   W1t    = (u16*)alloc((size_t)NE * DIM * FF * 2);
    u16*   W2t    = (u16*)alloc((size_t)NE * DIM * FF * 2);
    u16*   hbuf   = (u16*)alloc((size_t)NTOK * FF * 2);
    float* probs  = (float*)alloc((size_t)NTOK * 4 * 4);
    int*   tlist  = (int*)alloc((size_t)NE * NTOK * 4);
    int*   eid    = (int*)alloc((size_t)NTOK * 4);
    int*   counts = (int*)alloc(256);

    hipMemsetAsync(counts, 0, 256, stream);
    gate_kernel<<<NTOK / 4, 256, 0, stream>>>(x, gw, probs, counts, tlist, eid, xbf);
    finalize_kernel<<<1, 256, 0, stream>>>((const float4*)probs, counts,
                                           out + (size_t)NTOK * DIM);
    transpose_convert_kernel<<<dim3(FF / 64, DIM / 64, NE), 256, 0, stream>>>(W1, W1t, DIM, FF);
    transpose_convert_kernel<<<dim3(DIM / 64, FF / 64, NE), 256, 0, stream>>>(W2, W2t, FF, DIM);
    init_out_kernel<<<(NTOK * DIM / 4) / 256, 256, 0, stream>>>(b2, eid, (float4*)out);

    // GEMM1: K=768, N=3072. grid = 32 rt * (12 ctl * 8 xcd) = 3072, rt slowest
    moe_gemm<DIM, FF, 1, 1, 0><<<32 * 96, 256, 0, stream>>>(
        xbf, W1t, b1, counts, tlist, hbuf, nullptr);
    // GEMM2: K=3072 split 4, N=768. grid = 32 rt * (12 q * 8 xcd) = 3072, rt slowest
    moe_gemm<FF, DIM, 4, 0, 1><<<32 * 96, 256, 0, stream>>>(
        hbuf, W2t, b2, counts, tlist, nullptr, out);
}

// Round 6
// 180.111 us; speedup vs baseline: 1.1860x; 1.1860x over previous
//
#include <hip/hip_runtime.h>
#include <hip/hip_bf16.h>
#include <stdint.h>
#include <math.h>

#define NTOK 4096
#define DIM 768
#define FF 3072
#define NE 4
#define MAXGT 36               // max total 128-row tiles over all experts (<=35+1)

typedef __attribute__((ext_vector_type(8))) short bf16x8;
typedef __attribute__((ext_vector_type(4))) float f32x4;
typedef unsigned short u16;

static __device__ __forceinline__ u16 f2bf(float f) {
    union { float f; unsigned u; } c; c.f = f;
    unsigned r = (c.u + 0x7FFFu + ((c.u >> 16) & 1u)) >> 16;
    return (u16)r;
}
static __device__ __forceinline__ float bf2f(u16 v) {
    union { unsigned u; float f; } c; c.u = ((unsigned)v) << 16;
    return c.f;
}

// Abramowitz-Stegun 7.1.26, |abs err| <= 1.5e-7
static __device__ __forceinline__ float fast_erff(float x) {
    float ax = fabsf(x);
    float t = 1.0f / (1.0f + 0.3275911f * ax);
    float p = ((((1.061405429f * t - 1.453152027f) * t) + 1.421413741f) * t
               - 0.284496736f) * t + 0.254829592f;
    float y = 1.0f - p * t * __expf(-ax * ax);
    return copysignf(y, x);
}

#define GLD_LDS16(g, l) __builtin_amdgcn_global_load_lds( \
    (const __attribute__((address_space(1))) void*)(g),   \
    (__attribute__((address_space(3))) void*)(l), 16, 0, 0)

// Packed-chunk swizzle: a 128x32 bf16 K-step tile = 8KB chunk of 512 16B-units.
// Element-run (row r, k-chunk c[0..3]) lives at unit j = (r*4 + c) ^ (r&7).

// ------- gating (fused with x->bf16 conversion) -------
__global__ __launch_bounds__(256) void gate_kernel(
    const float* __restrict__ x, const float* __restrict__ gw,
    float* __restrict__ probs, int* __restrict__ counts, int* __restrict__ tlist,
    u16* __restrict__ xbf)
{
    const int wid = threadIdx.x >> 6, lane = threadIdx.x & 63;
    const int n = blockIdx.x * 4 + wid;
    const float4* xr4 = (const float4*)(x + (size_t)n * DIM);
    float a0 = 0.f, a1 = 0.f, a2 = 0.f, a3 = 0.f;
    float4 xv[3];
    #pragma unroll
    for (int c = 0; c < 3; c++) {
        float4 v = xr4[c * 64 + lane];
        xv[c] = v;
        const float4 g0 = ((const float4*)(gw + 0 * DIM))[c * 64 + lane];
        const float4 g1 = ((const float4*)(gw + 1 * DIM))[c * 64 + lane];
        const float4 g2 = ((const float4*)(gw + 2 * DIM))[c * 64 + lane];
        const float4 g3 = ((const float4*)(gw + 3 * DIM))[c * 64 + lane];
        a0 += v.x * g0.x + v.y * g0.y + v.z * g0.z + v.w * g0.w;
        a1 += v.x * g1.x + v.y * g1.y + v.z * g1.z + v.w * g1.w;
        a2 += v.x * g2.x + v.y * g2.y + v.z * g2.z + v.w * g2.w;
        a3 += v.x * g3.x + v.y * g3.y + v.z * g3.z + v.w * g3.w;
    }
    #pragma unroll
    for (int c = 0; c < 3; c++) {
        ushort4 o;
        o.x = f2bf(xv[c].x); o.y = f2bf(xv[c].y);
        o.z = f2bf(xv[c].z); o.w = f2bf(xv[c].w);
        *(ushort4*)(xbf + (size_t)n * DIM + (c * 64 + lane) * 4) = o;
    }
    #pragma unroll
    for (int off = 32; off > 0; off >>= 1) {
        a0 += __shfl_xor(a0, off);
        a1 += __shfl_xor(a1, off);
        a2 += __shfl_xor(a2, off);
        a3 += __shfl_xor(a3, off);
    }
    if (lane == 0) {
        float l[4] = {a0, a1, a2, a3};
        float m = fmaxf(fmaxf(l[0], l[1]), fmaxf(l[2], l[3]));
        float p[4], s = 0.f;
        #pragma unroll
        for (int e = 0; e < 4; e++) { p[e] = expf(l[e] - m); s += p[e]; }
        float inv = 1.f / s;
        int amax = 0; float best = l[0];
        #pragma unroll
        for (int e = 1; e < 4; e++) if (l[e] > best) { best = l[e]; amax = e; }
        #pragma unroll
        for (int e = 0; e < 4; e++) probs[n * 4 + e] = p[e] * inv;
        int pos = atomicAdd(&counts[amax], 1);
        tlist[amax * NTOK + pos] = n;
    }
}

// ------- balance loss + gate_load tail + tile-base prefix (tb -> counts[8..12]) -------
__global__ __launch_bounds__(256) void finalize_kernel(
    const float4* __restrict__ probs4, int* __restrict__ counts,
    float* __restrict__ tail)
{
    __shared__ float sdata[256 * 4];
    float p0 = 0.f, p1 = 0.f, p2 = 0.f, p3 = 0.f;
    for (int n = threadIdx.x; n < NTOK; n += 256) {
        float4 v = probs4[n];
        p0 += v.x; p1 += v.y; p2 += v.z; p3 += v.w;
    }
    sdata[threadIdx.x * 4 + 0] = p0;
    sdata[threadIdx.x * 4 + 1] = p1;
    sdata[threadIdx.x * 4 + 2] = p2;
    sdata[threadIdx.x * 4 + 3] = p3;
    __syncthreads();
    for (int s = 128; s > 0; s >>= 1) {
        if ((int)threadIdx.x < s) {
            #pragma unroll
            for (int e = 0; e < 4; e++)
                sdata[threadIdx.x * 4 + e] += sdata[(threadIdx.x + s) * 4 + e];
        }
        __syncthreads();
    }
    if (threadIdx.x == 0) {
        float bl = 0.f;
        int tb = 0;
        counts[8] = 0;
        #pragma unroll
        for (int e = 0; e < 4; e++) {
            int c = counts[e];
            bl += (sdata[e] / (float)NTOK) * ((float)c / (float)NTOK);
            tb += (c + 127) >> 7;
            counts[9 + e] = tb;
        }
        bl *= (float)NE;
        tail[0] = bl;
        #pragma unroll
        for (int e = 0; e < 4; e++) tail[1 + e] = (float)counts[e];
    }
}

// ---- fused W1/W2: fp32 [E][K][N] -> packed-swizzled bf16 tiles [e][ct][t][8KB] ----
__global__ __launch_bounds__(256) void transpose_pack_kernel(
    const float* __restrict__ W1, const float* __restrict__ W2,
    u16* __restrict__ W1tp, u16* __restrict__ W2tp)
{
    __shared__ float tile[64 * 65];
    const int half = blockIdx.x / 2304;          // 0: W1, 1: W2
    const int b2 = blockIdx.x % 2304;
    const int e = b2 / 576;
    const int rem = b2 % 576;
    int cx, ry, Ccols, NS, CT;
    const float* src;
    u16* dst;
    if (half == 0) {
        cx = rem % 48; ry = rem / 48;            // C=3072 (n), R=768 (k)
        Ccols = FF; NS = DIM / 32; CT = FF / 128;
        src = W1 + (size_t)e * DIM * FF; dst = W1tp;
    } else {
        cx = rem % 12; ry = rem / 12;            // C=768 (n), R=3072 (k)
        Ccols = DIM; NS = FF / 32; CT = DIM / 128;
        src = W2 + (size_t)e * DIM * FF; dst = W2tp;
    }
    const int r0 = ry * 64, c0 = cx * 64;        // r0: k-offset, c0: n-offset
    #pragma unroll
    for (int p = 0; p < 4; ++p) {
        int f = p * 256 + threadIdx.x;
        int row = f >> 4, c4 = (f & 15) * 4;
        float4 v = *(const float4*)(src + (size_t)(r0 + row) * Ccols + c0 + c4);
        tile[row * 65 + c4 + 0] = v.x;
        tile[row * 65 + c4 + 1] = v.y;
        tile[row * 65 + c4 + 2] = v.z;
        tile[row * 65 + c4 + 3] = v.w;
    }
    __syncthreads();
    #pragma unroll
    for (int p = 0; p < 2; ++p) {
        int u = p * 256 + threadIdx.x;
        int orow = u >> 3, g = (u & 7) * 8;      // orow: n-local, g: k-run base
        bf16x8 v;
        #pragma unroll
        for (int j = 0; j < 8; ++j)
            v[j] = (short)f2bf(tile[(g + j) * 65 + orow]);
        const int n = c0 + orow;
        const int ct = n >> 7, rr = n & 127;
        const int k = r0 + g;
        const int t = k >> 5, c = (k >> 3) & 3;
        const int unit = ((rr * 4 + c) ^ (rr & 7));
        *(bf16x8*)(dst + ((size_t)((e * CT + ct) * NS + t) << 12) + unit * 8) = v;
    }
}

// ---- gather token rows into packed-swizzled A chunks: [gt][t][8KB] ----
__global__ __launch_bounds__(256) void packA_kernel(
    const u16* __restrict__ xbf, const int* __restrict__ counts,
    const int* __restrict__ tlist, u16* __restrict__ Apack)
{
    const int gt = blockIdx.x >> 3, pp = blockIdx.x & 7;
    const int* tb = counts + 8;
    if (gt >= tb[4]) return;
    const int e = (gt >= tb[1]) + (gt >= tb[2]) + (gt >= tb[3]);
    const int rt = gt - tb[e];
    const int cnt = counts[e];
    for (int u = pp * 1536 + threadIdx.x; u < (pp + 1) * 1536; u += 256) {
        const int t = u >> 9, j = u & 511;
        const int r = ((j >> 3) << 1) | (((j >> 2) & 1) ^ ((j >> 4) & 1));
        const int c = (j & 3) ^ (r & 3);
        const int pos = rt * 128 + r;
        const int tok = tlist[e * NTOK + min(pos, cnt - 1)];
        *(bf16x8*)(Apack + ((size_t)(gt * (DIM / 32) + t) << 12) + j * 8) =
            *(const bf16x8*)(xbf + (size_t)tok * DIM + t * 32 + c * 8);
    }
}

// ---- dense MFMA GEMM on packed buffers, 128x128 tile, 4 waves, depth-2, 3 bufs ----
// bx = gt*QN + q (q>=QUSE exits; QN%8==0 so q pins XCD; B-panels pinned per-XCD).
// A chunks: Apk + (gt*(KD/32) + ks*NS + t)*4096.  B: Bpk + ((e*CTN+ct)*(KD/32)+ks*NS+t)*4096.
// GELU_EP=1: out = packed-swizzled bf16 chunks (GEMM2's A layout).  else: bf16 partials.
template <int KD, int NCOL, int KSPLIT, int GELU_EP, int QN, int QUSE>
__global__ __launch_bounds__(256, 3) void moe_gemm(
    const u16* __restrict__ Apk, const u16* __restrict__ Bpk,
    const float* __restrict__ bias, const int* __restrict__ counts,
    u16* __restrict__ Out, int pstride)
{
    constexpr int NS = KD / KSPLIT / 32;
    constexpr int CTN = NCOL / 128;

    const int gt = blockIdx.x / QN;
    const int q = blockIdx.x % QN;
    if (q >= QUSE) return;
    const int* tb = counts + 8;
    if (gt >= tb[4]) return;
    const int e = (gt >= tb[1]) + (gt >= tb[2]) + (gt >= tb[3]);
    const int ks = q / CTN;
    const int ct = q % CTN;

    __shared__ __align__(16) u16 As[3][4096];
    __shared__ __align__(16) u16 Bs[3][4096];

    const int tid = threadIdx.x;
    const int lane = tid & 63;
    const int w = tid >> 6;

    const u16* pA = Apk + ((size_t)(gt * (KD / 32) + ks * NS) << 12);
    const u16* pB = Bpk + ((size_t)((e * CTN + ct) * (KD / 32) + ks * NS) << 12);
    const int so = w * 512;                      // per-wave staging offset (u16)

    const int wm = w >> 1, wn = w & 1;
    const int fr = lane & 15, fg = lane >> 4;
    const int laneoff = (fr * 64 + fg * 16) ^ ((fr & 7) << 4);

    f32x4 acc[4][4];
    #pragma unroll
    for (int i = 0; i < 4; i++)
        #pragma unroll
        for (int j = 0; j < 4; j++) acc[i][j] = (f32x4){0.f, 0.f, 0.f, 0.f};

    auto stage = [&](int T) {
        const int b = T % 3;
        const u16* sa = pA + (T << 12);
        const u16* sb = pB + (T << 12);
        GLD_LDS16(sa + so, &As[b][so]);
        GLD_LDS16(sa + 2048 + so, &As[b][2048 + so]);
        GLD_LDS16(sb + so, &Bs[b][so]);
        GLD_LDS16(sb + 2048 + so, &Bs[b][2048 + so]);
    };
    auto compute = [&](int T) {
        const char* Ab = (const char*)&As[T % 3][0];
        const char* Bb = (const char*)&Bs[T % 3][0];
        bf16x8 af[4], bg[4];
        #pragma unroll
        for (int m4 = 0; m4 < 4; m4++)
            af[m4] = *(const bf16x8*)(Ab + wm * 4096 + m4 * 1024 + laneoff);
        #pragma unroll
        for (int n4 = 0; n4 < 4; n4++)
            bg[n4] = *(const bf16x8*)(Bb + wn * 4096 + n4 * 1024 + laneoff);
        #pragma unroll
        for (int m4 = 0; m4 < 4; m4++)
            #pragma unroll
            for (int n4 = 0; n4 < 4; n4++)
                acc[m4][n4] = __builtin_amdgcn_mfma_f32_16x16x32_bf16(
                    af[m4], bg[n4], acc[m4][n4], 0, 0, 0);
    };

    stage(0); stage(1);
    for (int t = 0; t < NS; ++t) {
        if (t < NS - 1)
            asm volatile("s_waitcnt vmcnt(4)" ::: "memory");
        else
            asm volatile("s_waitcnt vmcnt(0)" ::: "memory");
        __builtin_amdgcn_sched_barrier(0);
        __builtin_amdgcn_s_barrier();
        __builtin_amdgcn_sched_barrier(0);
        if (t + 2 < NS) stage(t + 2);
        compute(t);
    }

    // epilogue: C/D layout col = fr, row = fg*4 + reg. Pad rows written too (skipped later).
    #pragma unroll
    for (int m4 = 0; m4 < 4; m4++) {
        #pragma unroll
        for (int r2 = 0; r2 < 4; r2++) {
            const int row = wm * 64 + m4 * 16 + fg * 4 + r2;
            #pragma unroll
            for (int n4 = 0; n4 < 4; n4++) {
                const int colg = wn * 64 + n4 * 16 + fr;
                const int col = ct * 128 + colg;
                float v = acc[m4][n4][r2];
                if (GELU_EP) {
                    v += bias[e * NCOL + col];
                    v = 0.5f * v * (1.f + fast_erff(v * 0.70710678118654752f));
                    // write in GEMM2's packed-A layout: chunk gt*96 + col/32
                    const int unit = ((row * 4 + ((col >> 3) & 3)) ^ (row & 7));
                    Out[((size_t)(gt * (NCOL / 32) + (col >> 5)) << 12) + unit * 8 +
                        (col & 7)] = f2bf(v);
                } else {
                    Out[(size_t)ks * pstride + (size_t)(gt * 128 + row) * NCOL + col] =
                        f2bf(v);
                }
            }
        }
    }
}

// ---- reduce: out[tok] = part0 + part1 + b2[e]  (scatter via tlist) ----
__global__ __launch_bounds__(256) void reduce_kernel(
    const u16* __restrict__ part, const float* __restrict__ b2,
    const int* __restrict__ counts, const int* __restrict__ tlist,
    float* __restrict__ out, int pstride)
{
    const int idx = blockIdx.x * 256 + threadIdx.x;    // over MAXGT*128 * 96
    const int gpos = idx / 96, c8 = idx % 96;
    const int gt = gpos >> 7;
    const int* tb = counts + 8;
    if (gt >= tb[4]) return;
    const int e = (gt >= tb[1]) + (gt >= tb[2]) + (gt >= tb[3]);
    const int pos = (gt - tb[e]) * 128 + (gpos & 127);
    if (pos >= counts[e]) return;
    const int tok = tlist[e * NTOK + pos];
    bf16x8 p0 = *(const bf16x8*)(part + (size_t)gpos * DIM + c8 * 8);
    bf16x8 p1 = *(const bf16x8*)(part + (size_t)pstride + (size_t)gpos * DIM + c8 * 8);
    const float* bb = b2 + e * DIM + c8 * 8;
    float* op = out + (size_t)tok * DIM + c8 * 8;
    #pragma unroll
    for (int i = 0; i < 8; i++)
        op[i] = bf2f((u16)p0[i]) + bf2f((u16)p1[i]) + bb[i];
}

extern "C" void kernel_launch(void* const* d_in, const int* in_sizes, int n_in,
                              void* d_out, int out_size, void* d_ws, size_t ws_size,
                              hipStream_t stream) {
    const float* x  = (const float*)d_in[0];
    const float* gw = (const float*)d_in[3];
    const float* W1 = (const float*)d_in[4];
    const float* b1 = (const float*)d_in[5];
    const float* W2 = (const float*)d_in[6];
    const float* b2 = (const float*)d_in[7];
    float* out = (float*)d_out;

    char* ws = (char*)d_ws;
    size_t o = 0;
    auto alloc = [&](size_t bytes) -> void* {
        void* p = ws + o;
        o = (o + bytes + 255) & ~(size_t)255;
        return p;
    };
    u16*   xbf    = (u16*)alloc((size_t)NTOK * DIM * 2);
    u16*   W1tp   = (u16*)alloc((size_t)NE * DIM * FF * 2);           // dead after GEMM1
    u16*   W2tp   = (u16*)alloc((size_t)NE * DIM * FF * 2);
    u16*   hbuf   = (u16*)alloc((size_t)MAXGT * 128 * FF * 2);        // packed-swizzled
    u16*   Apack  = (u16*)alloc((size_t)MAXGT * 128 * DIM * 2);
    float* probs  = (float*)alloc((size_t)NTOK * 4 * 4);
    int*   tlist  = (int*)alloc((size_t)NE * NTOK * 4);
    int*   counts = (int*)alloc(256);
    // partials alias W1tp (14.2 MB <= 18.9 MB, W1tp rewritten every call before use)
    u16*   part   = (u16*)W1tp;
    const int pstride = MAXGT * 128 * DIM;                            // u16 per ks-slice

    hipMemsetAsync(counts, 0, 256, stream);
    gate_kernel<<<NTOK / 4, 256, 0, stream>>>(x, gw, probs, counts, tlist, xbf);
    finalize_kernel<<<1, 256, 0, stream>>>((const float4*)probs, counts,
                                           out + (size_t)NTOK * DIM);
    transpose_pack_kernel<<<4608, 256, 0, stream>>>(W1, W2, W1tp, W2tp);
    packA_kernel<<<MAXGT * 8, 256, 0, stream>>>(xbf, counts, tlist, Apack);

    // GEMM1: K=768, N=3072, KSPLIT=1, QN=QUSE=24 (ct). grid 36*24=864
    moe_gemm<DIM, FF, 1, 1, 24, 24><<<MAXGT * 24, 256, 0, stream>>>(
        Apack, W1tp, b1, counts, hbuf, 0);
    // GEMM2: K=3072, N=768, KSPLIT=2, QN=16, QUSE=12 (ks*6+ct). grid 36*16=576
    moe_gemm<FF, DIM, 2, 0, 16, 12><<<MAXGT * 16, 256, 0, stream>>>(
        hbuf, W2tp, b2, counts, part, pstride);

    reduce_kernel<<<(MAXGT * 128 * 96) / 256, 256, 0, stream>>>(
        part, b2, counts, tlist, out, pstride);
}

// Round 7
// 130.694 us; speedup vs baseline: 1.6345x; 1.3781x over previous
//
#include <hip/hip_runtime.h>
#include <hip/hip_bf16.h>
#include <stdint.h>
#include <math.h>

#define NTOK 4096
#define DIM 768
#define FF 3072
#define NE 4
#define MAXGT 36               // max total 128-row tiles over all experts (<=35+1)

typedef __attribute__((ext_vector_type(8))) short bf16x8;
typedef __attribute__((ext_vector_type(4))) float f32x4;
typedef unsigned short u16;

static __device__ __forceinline__ u16 f2bf(float f) {
    union { float f; unsigned u; } c; c.f = f;
    unsigned r = (c.u + 0x7FFFu + ((c.u >> 16) & 1u)) >> 16;
    return (u16)r;
}
static __device__ __forceinline__ float bf2f(u16 v) {
    union { unsigned u; float f; } c; c.u = ((unsigned)v) << 16;
    return c.f;
}

// Abramowitz-Stegun 7.1.26, |abs err| <= 1.5e-7
static __device__ __forceinline__ float fast_erff(float x) {
    float ax = fabsf(x);
    float t = 1.0f / (1.0f + 0.3275911f * ax);
    float p = ((((1.061405429f * t - 1.453152027f) * t) + 1.421413741f) * t
               - 0.284496736f) * t + 0.254829592f;
    float y = 1.0f - p * t * __expf(-ax * ax);
    return copysignf(y, x);
}

#define GLD_LDS16(g, l) __builtin_amdgcn_global_load_lds( \
    (const __attribute__((address_space(1))) void*)(g),   \
    (__attribute__((address_space(3))) void*)(l), 16, 0, 0)

// Packed-chunk swizzle: a 128x32 bf16 K-step tile = 8KB chunk of 512 16B-units.
// Element-run (row r, k-chunk c[0..3]) lives at unit j = (r*4 + c) ^ (r&7).

// ------- gating (fused with x->bf16 conversion): NO atomics, writes probs+eid -------
__global__ __launch_bounds__(256) void gate_kernel(
    const float* __restrict__ x, const float* __restrict__ gw,
    float* __restrict__ probs, int* __restrict__ eid, u16* __restrict__ xbf)
{
    const int wid = threadIdx.x >> 6, lane = threadIdx.x & 63;
    const int n = blockIdx.x * 4 + wid;
    const float4* xr4 = (const float4*)(x + (size_t)n * DIM);
    float a0 = 0.f, a1 = 0.f, a2 = 0.f, a3 = 0.f;
    float4 xv[3];
    #pragma unroll
    for (int c = 0; c < 3; c++) {
        float4 v = xr4[c * 64 + lane];
        xv[c] = v;
        const float4 g0 = ((const float4*)(gw + 0 * DIM))[c * 64 + lane];
        const float4 g1 = ((const float4*)(gw + 1 * DIM))[c * 64 + lane];
        const float4 g2 = ((const float4*)(gw + 2 * DIM))[c * 64 + lane];
        const float4 g3 = ((const float4*)(gw + 3 * DIM))[c * 64 + lane];
        a0 += v.x * g0.x + v.y * g0.y + v.z * g0.z + v.w * g0.w;
        a1 += v.x * g1.x + v.y * g1.y + v.z * g1.z + v.w * g1.w;
        a2 += v.x * g2.x + v.y * g2.y + v.z * g2.z + v.w * g2.w;
        a3 += v.x * g3.x + v.y * g3.y + v.z * g3.z + v.w * g3.w;
    }
    #pragma unroll
    for (int c = 0; c < 3; c++) {
        ushort4 o;
        o.x = f2bf(xv[c].x); o.y = f2bf(xv[c].y);
        o.z = f2bf(xv[c].z); o.w = f2bf(xv[c].w);
        *(ushort4*)(xbf + (size_t)n * DIM + (c * 64 + lane) * 4) = o;
    }
    #pragma unroll
    for (int off = 32; off > 0; off >>= 1) {
        a0 += __shfl_xor(a0, off);
        a1 += __shfl_xor(a1, off);
        a2 += __shfl_xor(a2, off);
        a3 += __shfl_xor(a3, off);
    }
    if (lane == 0) {
        float l[4] = {a0, a1, a2, a3};
        float m = fmaxf(fmaxf(l[0], l[1]), fmaxf(l[2], l[3]));
        float p[4], s = 0.f;
        #pragma unroll
        for (int e = 0; e < 4; e++) { p[e] = expf(l[e] - m); s += p[e]; }
        float inv = 1.f / s;
        int amax = 0; float best = l[0];
        #pragma unroll
        for (int e = 1; e < 4; e++) if (l[e] > best) { best = l[e]; amax = e; }
        #pragma unroll
        for (int e = 0; e < 4; e++) probs[n * 4 + e] = p[e] * inv;
        eid[n] = amax;
    }
}

// ---- single-block deterministic scan: tlist (token-sorted), counts, tile bases,
// ---- balance loss + gate_load tail (replaces finalize + gate atomics) ----
__global__ __launch_bounds__(1024) void scan_kernel(
    const int4* __restrict__ eid4, const float4* __restrict__ probs4,
    int* __restrict__ counts, int* __restrict__ tlist, float* __restrict__ tail)
{
    __shared__ int4 sc[2][1024];
    __shared__ float4 sp[1024];
    const int t = threadIdx.x;
    const int4 e4 = eid4[t];                 // tokens 4t .. 4t+3
    int es[4] = {e4.x, e4.y, e4.z, e4.w};
    int c[4] = {0, 0, 0, 0};
    #pragma unroll
    for (int i = 0; i < 4; i++) c[es[i]]++;
    sc[0][t] = make_int4(c[0], c[1], c[2], c[3]);
    float4 ps = probs4[4 * t + 0];
    #pragma unroll
    for (int i = 1; i < 4; i++) {
        float4 v = probs4[4 * t + i];
        ps.x += v.x; ps.y += v.y; ps.z += v.z; ps.w += v.w;
    }
    sp[t] = ps;
    __syncthreads();
    // Hillis-Steele inclusive scan over 1024 threads x 4 experts
    int buf = 0;
    for (int off = 1; off < 1024; off <<= 1) {
        int4 v = sc[buf][t];
        if (t >= off) {
            int4 u = sc[buf][t - off];
            v.x += u.x; v.y += u.y; v.z += u.z; v.w += u.w;
        }
        sc[buf ^ 1][t] = v;
        buf ^= 1;
        __syncthreads();
    }
    const int4 incl = sc[buf][t];
    const int4 tot4 = sc[buf][1023];
    int base[4] = {incl.x - c[0], incl.y - c[1], incl.z - c[2], incl.w - c[3]};
    int run[4] = {0, 0, 0, 0};
    #pragma unroll
    for (int i = 0; i < 4; i++) {
        const int e = es[i];
        tlist[e * NTOK + base[e] + run[e]] = 4 * t + i;
        run[e]++;
    }
    // probs tree-reduce for balance loss
    for (int s = 512; s > 0; s >>= 1) {
        if (t < s) {
            float4 a = sp[t], b = sp[t + s];
            a.x += b.x; a.y += b.y; a.z += b.z; a.w += b.w;
            sp[t] = a;
        }
        __syncthreads();
    }
    if (t == 0) {
        int tot[4] = {tot4.x, tot4.y, tot4.z, tot4.w};
        float Ps[4] = {sp[0].x, sp[0].y, sp[0].z, sp[0].w};
        int tb = 0;
        counts[8] = 0;
        float bl = 0.f;
        #pragma unroll
        for (int e = 0; e < 4; e++) {
            counts[e] = tot[e];
            bl += (Ps[e] / (float)NTOK) * ((float)tot[e] / (float)NTOK);
            tb += (tot[e] + 127) >> 7;
            counts[9 + e] = tb;
        }
        tail[0] = bl * (float)NE;
        #pragma unroll
        for (int e = 0; e < 4; e++) tail[1 + e] = (float)tot[e];
    }
}

// ---- fused W1/W2: fp32 [E][K][N] -> packed-swizzled bf16 tiles [e][ct][t][8KB] ----
__global__ __launch_bounds__(256) void transpose_pack_kernel(
    const float* __restrict__ W1, const float* __restrict__ W2,
    u16* __restrict__ W1tp, u16* __restrict__ W2tp)
{
    __shared__ float tile[64 * 65];
    const int half = blockIdx.x / 2304;          // 0: W1, 1: W2
    const int b2 = blockIdx.x % 2304;
    const int e = b2 / 576;
    const int rem = b2 % 576;
    int cx, ry, Ccols, NS, CT;
    const float* src;
    u16* dst;
    if (half == 0) {
        cx = rem % 48; ry = rem / 48;            // C=3072 (n), R=768 (k)
        Ccols = FF; NS = DIM / 32; CT = FF / 128;
        src = W1 + (size_t)e * DIM * FF; dst = W1tp;
    } else {
        cx = rem % 12; ry = rem / 12;            // C=768 (n), R=3072 (k)
        Ccols = DIM; NS = FF / 32; CT = DIM / 128;
        src = W2 + (size_t)e * DIM * FF; dst = W2tp;
    }
    const int r0 = ry * 64, c0 = cx * 64;        // r0: k-offset, c0: n-offset
    #pragma unroll
    for (int p = 0; p < 4; ++p) {
        int f = p * 256 + threadIdx.x;
        int row = f >> 4, c4 = (f & 15) * 4;
        float4 v = *(const float4*)(src + (size_t)(r0 + row) * Ccols + c0 + c4);
        tile[row * 65 + c4 + 0] = v.x;
        tile[row * 65 + c4 + 1] = v.y;
        tile[row * 65 + c4 + 2] = v.z;
        tile[row * 65 + c4 + 3] = v.w;
    }
    __syncthreads();
    #pragma unroll
    for (int p = 0; p < 2; ++p) {
        int u = p * 256 + threadIdx.x;
        int orow = u >> 3, g = (u & 7) * 8;      // orow: n-local, g: k-run base
        bf16x8 v;
        #pragma unroll
        for (int j = 0; j < 8; ++j)
            v[j] = (short)f2bf(tile[(g + j) * 65 + orow]);
        const int n = c0 + orow;
        const int ct = n >> 7, rr = n & 127;
        const int k = r0 + g;
        const int t = k >> 5, c = (k >> 3) & 3;
        const int unit = ((rr * 4 + c) ^ (rr & 7));
        *(bf16x8*)(dst + ((size_t)((e * CT + ct) * NS + t) << 12) + unit * 8) = v;
    }
}

// ---- gather token rows into packed-swizzled A chunks: [gt][t][8KB] ----
__global__ __launch_bounds__(256) void packA_kernel(
    const u16* __restrict__ xbf, const int* __restrict__ counts,
    const int* __restrict__ tlist, u16* __restrict__ Apack)
{
    const int gt = blockIdx.x >> 3, pp = blockIdx.x & 7;
    const int* tb = counts + 8;
    if (gt >= tb[4]) return;
    const int e = (gt >= tb[1]) + (gt >= tb[2]) + (gt >= tb[3]);
    const int rt = gt - tb[e];
    const int cnt = counts[e];
    for (int u = pp * 1536 + threadIdx.x; u < (pp + 1) * 1536; u += 256) {
        const int t = u >> 9, j = u & 511;
        const int r = ((j >> 3) << 1) | (((j >> 2) & 1) ^ ((j >> 4) & 1));
        const int c = (j & 3) ^ (r & 3);
        const int pos = rt * 128 + r;
        const int tok = tlist[e * NTOK + min(pos, cnt - 1)];
        *(bf16x8*)(Apack + ((size_t)(gt * (DIM / 32) + t) << 12) + j * 8) =
            *(const bf16x8*)(xbf + (size_t)tok * DIM + t * 32 + c * 8);
    }
}

// ---- dense MFMA GEMM on packed buffers, 128x128 tile, 4 waves, depth-2, 3 bufs ----
template <int KD, int NCOL, int KSPLIT, int GELU_EP, int QN, int QUSE>
__global__ __launch_bounds__(256, 3) void moe_gemm(
    const u16* __restrict__ Apk, const u16* __restrict__ Bpk,
    const float* __restrict__ bias, const int* __restrict__ counts,
    u16* __restrict__ Out, int pstride)
{
    constexpr int NS = KD / KSPLIT / 32;
    constexpr int CTN = NCOL / 128;

    const int gt = blockIdx.x / QN;
    const int q = blockIdx.x % QN;
    if (q >= QUSE) return;
    const int* tb = counts + 8;
    if (gt >= tb[4]) return;
    const int e = (gt >= tb[1]) + (gt >= tb[2]) + (gt >= tb[3]);
    const int ks = q / CTN;
    const int ct = q % CTN;

    __shared__ __align__(16) u16 As[3][4096];
    __shared__ __align__(16) u16 Bs[3][4096];

    const int tid = threadIdx.x;
    const int lane = tid & 63;
    const int w = tid >> 6;

    const u16* pA = Apk + ((size_t)(gt * (KD / 32) + ks * NS) << 12);
    const u16* pB = Bpk + ((size_t)((e * CTN + ct) * (KD / 32) + ks * NS) << 12);
    const int so = w * 512;                      // per-wave staging offset (u16)

    const int wm = w >> 1, wn = w & 1;
    const int fr = lane & 15, fg = lane >> 4;
    const int laneoff = (fr * 64 + fg * 16) ^ ((fr & 7) << 4);

    f32x4 acc[4][4];
    #pragma unroll
    for (int i = 0; i < 4; i++)
        #pragma unroll
        for (int j = 0; j < 4; j++) acc[i][j] = (f32x4){0.f, 0.f, 0.f, 0.f};

    auto stage = [&](int T) {
        const int b = T % 3;
        const u16* sa = pA + (T << 12);
        const u16* sb = pB + (T << 12);
        GLD_LDS16(sa + so, &As[b][so]);
        GLD_LDS16(sa + 2048 + so, &As[b][2048 + so]);
        GLD_LDS16(sb + so, &Bs[b][so]);
        GLD_LDS16(sb + 2048 + so, &Bs[b][2048 + so]);
    };
    auto compute = [&](int T) {
        const char* Ab = (const char*)&As[T % 3][0];
        const char* Bb = (const char*)&Bs[T % 3][0];
        bf16x8 af[4], bg[4];
        #pragma unroll
        for (int m4 = 0; m4 < 4; m4++)
            af[m4] = *(const bf16x8*)(Ab + wm * 4096 + m4 * 1024 + laneoff);
        #pragma unroll
        for (int n4 = 0; n4 < 4; n4++)
            bg[n4] = *(const bf16x8*)(Bb + wn * 4096 + n4 * 1024 + laneoff);
        #pragma unroll
        for (int m4 = 0; m4 < 4; m4++)
            #pragma unroll
            for (int n4 = 0; n4 < 4; n4++)
                acc[m4][n4] = __builtin_amdgcn_mfma_f32_16x16x32_bf16(
                    af[m4], bg[n4], acc[m4][n4], 0, 0, 0);
    };

    stage(0); stage(1);
    for (int t = 0; t < NS; ++t) {
        if (t < NS - 1)
            asm volatile("s_waitcnt vmcnt(4)" ::: "memory");
        else
            asm volatile("s_waitcnt vmcnt(0)" ::: "memory");
        __builtin_amdgcn_sched_barrier(0);
        __builtin_amdgcn_s_barrier();
        __builtin_amdgcn_sched_barrier(0);
        if (t + 2 < NS) stage(t + 2);
        compute(t);
    }

    // epilogue: C/D layout col = fr, row = fg*4 + reg. Pad rows written too (skipped later).
    #pragma unroll
    for (int m4 = 0; m4 < 4; m4++) {
        #pragma unroll
        for (int r2 = 0; r2 < 4; r2++) {
            const int row = wm * 64 + m4 * 16 + fg * 4 + r2;
            #pragma unroll
            for (int n4 = 0; n4 < 4; n4++) {
                const int colg = wn * 64 + n4 * 16 + fr;
                const int col = ct * 128 + colg;
                float v = acc[m4][n4][r2];
                if (GELU_EP) {
                    v += bias[e * NCOL + col];
                    v = 0.5f * v * (1.f + fast_erff(v * 0.70710678118654752f));
                    const int unit = ((row * 4 + ((col >> 3) & 3)) ^ (row & 7));
                    Out[((size_t)(gt * (NCOL / 32) + (col >> 5)) << 12) + unit * 8 +
                        (col & 7)] = f2bf(v);
                } else {
                    Out[(size_t)ks * pstride + (size_t)(gt * 128 + row) * NCOL + col] =
                        f2bf(v);
                }
            }
        }
    }
}

// ---- reduce: out[tok] = part0 + part1 + b2[e]  (scatter via tlist) ----
__global__ __launch_bounds__(256) void reduce_kernel(
    const u16* __restrict__ part, const float* __restrict__ b2,
    const int* __restrict__ counts, const int* __restrict__ tlist,
    float* __restrict__ out, int pstride)
{
    const int idx = blockIdx.x * 256 + threadIdx.x;    // over MAXGT*128 * 96
    const int gpos = idx / 96, c8 = idx % 96;
    const int gt = gpos >> 7;
    const int* tb = counts + 8;
    if (gt >= tb[4]) return;
    const int e = (gt >= tb[1]) + (gt >= tb[2]) + (gt >= tb[3]);
    const int pos = (gt - tb[e]) * 128 + (gpos & 127);
    if (pos >= counts[e]) return;
    const int tok = tlist[e * NTOK + pos];
    bf16x8 p0 = *(const bf16x8*)(part + (size_t)gpos * DIM + c8 * 8);
    bf16x8 p1 = *(const bf16x8*)(part + (size_t)pstride + (size_t)gpos * DIM + c8 * 8);
    const float* bb = b2 + e * DIM + c8 * 8;
    float* op = out + (size_t)tok * DIM + c8 * 8;
    #pragma unroll
    for (int i = 0; i < 8; i++)
        op[i] = bf2f((u16)p0[i]) + bf2f((u16)p1[i]) + bb[i];
}

extern "C" void kernel_launch(void* const* d_in, const int* in_sizes, int n_in,
                              void* d_out, int out_size, void* d_ws, size_t ws_size,
                              hipStream_t stream) {
    const float* x  = (const float*)d_in[0];
    const float* gw = (const float*)d_in[3];
    const float* W1 = (const float*)d_in[4];
    const float* b1 = (const float*)d_in[5];
    const float* W2 = (const float*)d_in[6];
    const float* b2 = (const float*)d_in[7];
    float* out = (float*)d_out;

    char* ws = (char*)d_ws;
    size_t o = 0;
    auto alloc = [&](size_t bytes) -> void* {
        void* p = ws + o;
        o = (o + bytes + 255) & ~(size_t)255;
        return p;
    };
    u16*   xbf    = (u16*)alloc((size_t)NTOK * DIM * 2);
    u16*   W1tp   = (u16*)alloc((size_t)NE * DIM * FF * 2);           // dead after GEMM1
    u16*   W2tp   = (u16*)alloc((size_t)NE * DIM * FF * 2);
    u16*   hbuf   = (u16*)alloc((size_t)MAXGT * 128 * FF * 2);        // packed-swizzled
    u16*   Apack  = (u16*)alloc((size_t)MAXGT * 128 * DIM * 2);
    float* probs  = (float*)alloc((size_t)NTOK * 4 * 4);
    int*   tlist  = (int*)alloc((size_t)NE * NTOK * 4);
    int*   eid    = (int*)alloc((size_t)NTOK * 4);
    int*   counts = (int*)alloc(256);
    // partials alias W1tp (14.2 MB <= 18.9 MB, W1tp rewritten every call before use)
    u16*   part   = (u16*)W1tp;
    const int pstride = MAXGT * 128 * DIM;                            // u16 per ks-slice

    gate_kernel<<<NTOK / 4, 256, 0, stream>>>(x, gw, probs, eid, xbf);
    scan_kernel<<<1, 1024, 0, stream>>>((const int4*)eid, (const float4*)probs,
                                        counts, tlist, out + (size_t)NTOK * DIM);
    transpose_pack_kernel<<<4608, 256, 0, stream>>>(W1, W2, W1tp, W2tp);
    packA_kernel<<<MAXGT * 8, 256, 0, stream>>>(xbf, counts, tlist, Apack);

    // GEMM1: K=768, N=3072, KSPLIT=1, QN=QUSE=24 (ct). grid 36*24=864
    moe_gemm<DIM, FF, 1, 1, 24, 24><<<MAXGT * 24, 256, 0, stream>>>(
        Apack, W1tp, b1, counts, hbuf, 0);
    // GEMM2: K=3072, N=768, KSPLIT=2, QN=16, QUSE=12 (ks*6+ct). grid 36*16=576
    moe_gemm<FF, DIM, 2, 0, 16, 12><<<MAXGT * 16, 256, 0, stream>>>(
        hbuf, W2tp, b2, counts, part, pstride);

    reduce_kernel<<<(MAXGT * 128 * 96) / 256, 256, 0, stream>>>(
        part, b2, counts, tlist, out, pstride);
}